// Round 9
// baseline (381.951 us; speedup 1.0000x reference)
//
#include <hip/hip_runtime.h>

#define NL 16384          // row length
#define NB 64             // rows = blocks
#define NT 1024           // threads per block (16 waves = 4 waves/SIMD)
#define NC (NL / NT)      // 16 elements per thread == bits in the peak mask
#define NW (NT / 64)      // 16 waves
#define N_ITER 12
#define N_IMFS 6

#pragma clang fp contract(off)   // everything unfused EXCEPT the explicit fmaf

#define HSZ (NL + (NL >> 5))   // +1 float per 32: 2-way-max banking (free)
__device__ __forceinline__ int physi(int i) { return i + (i >> 5); }

#define FMAXV 3.402823466e38f

// Frozen bit-exact semantics (R6 value path, absmax 0.0).
// R7: +1 device sync/iter = +157us over 78 iters => ~2us per exposed device
// sync; ~150us of R6's 231 is barrier exposure. R8 (lag-1 at top of next
// iter): ZERO slack between post and poll -> still a full barrier, plus
// unpadded counter slots (poll/RMW line ping-pong) -> 277us, worse.
// R19: lag-2 via block-private global snapshot ring, depth 3 (L2-resident,
// 1.5MB/XCD). Pass C writes s_{it+1} to LDS AND ring[(it+1)%3]. conv_j need
// only resolve before pass C of iter j+2 overwrites ring slot j%3 -> two
// iterations (~5us) of post->poll slack -> poll finds counter complete, no
// spin. Recovery (rare, conv true): copy s_j from ring (res for j=0) into
// LDS. First-true-wins preserved => exact JAX latch semantics. t0 posts with
// NO wait; S5 already orders pass-C writes for next pass A (S6 dropped).
// Exposed waits left: conv_11 once per IMF. Flat decision lags one full IMF.
// Control slots padded to 64B. useRing=0 fallback = R8 lag-1 (correct).
__global__ __launch_bounds__(NT, 4) void emd_main(
    const float* __restrict__ x, float* __restrict__ out, char* __restrict__ ws,
    int useRing) {
  // ---- workspace: 64B-strided control + snapshot ring ----
  unsigned* scnt = (unsigned*)ws;           // [72] sd arrival counters (x16 u32)
  double*   sdsl = (double*)(ws + 8192);    // [72] {m2,h2} (x8 dbl stride)
  unsigned* fcnt = (unsigned*)(ws + 16384); // [6] flat arrival counters (x16)
  double*   flsl = (double*)(ws + 20480);   // [6] {S1..S4} (x8 dbl stride)
  float*    ring = (float*)(ws + 32768);    // [NB][3][NL] block-private

  __shared__ float hbuf[2 * HSZ];   // 135168 B double-buffered h
  __shared__ int wLU[NW], wLL[NW], wNU[NW], wNL[NW];
  __shared__ float wMx[NW], wMn[NW];
  __shared__ unsigned wCT[NW];
  __shared__ int eLU[NW], eLL[NW], eNU[NW], eNL[NW];
  __shared__ float eMx[NW], eMn[NW];
  __shared__ unsigned sTot;
  __shared__ double tA[NW], tB[NW], tC[NW], tD[NW];
  __shared__ int sFlag;

  const int t = threadIdx.x;
  const int lane = t & 63;
  const int wv = t >> 6;
  const int row = blockIdx.x;
  const int base = t * NC;
  const float* xr = x + (size_t)row * NL;
  float* res = out + (size_t)N_IMFS * NB * NL + (size_t)row * NL;
  float* myring = ring + (size_t)row * 3 * NL;
  const int LAG = useRing ? 2 : 1;

  int off = 0;   // current h buffer offset (0 or HSZ), globally uniform

  // init: h = x row (LDS, swizzled); res slab of d_out = x
  #pragma unroll
  for (int q = 0; q < NC / 4; q++) {
    int i0 = base + q * 4;
    float4 v = *(const float4*)&xr[i0];
    *(float4*)&hbuf[physi(i0)] = v;
    *(float4*)&res[i0] = v;
  }
  __syncthreads();

  bool done = false;

  for (int k = 0; k < N_IMFS; k++) {
    float* outk = out + (size_t)k * NB * NL + (size_t)row * NL;
    if (done) {  // resolved-done skip (uniform, no barriers, no posts)
      #pragma unroll
      for (int q = 0; q < NC / 4; q++)
        *(float4*)&outk[base + q * 4] = make_float4(0.f, 0.f, 0.f, 0.f);
      continue;
    }

    // ---------------- sifting (lag-LAG convergence) ----------------
    int fin = 0;
    for (int it = 0; it < N_ITER; it++) {
      float* hcur = hbuf + off;
      float* hnx  = hbuf + (off ^ HSZ);

      // pass A: chunked rolling walk -> peak masks + chunk summaries
      unsigned mU = 0, mL = 0;
      int lmU = -1, lmL = -1, cU = 0, cL = 0;
      float rmx = -FMAXV, rmn = FMAXV;
      {
        float hm = (base > 0) ? hcur[physi(base - 1)] : 0.0f;
        float4 cur = *(const float4*)&hcur[physi(base)];
        #define PKSTEP(J, HC, HP) { int i = base + (J);                     \
          bool in = (i > 0) && (i + 1 < NL);                                \
          if (in && hm < (HC) && (HC) > (HP)) { mU |= 1u << (J); lmU = i; cU++; } \
          if (in && hm > (HC) && (HC) < (HP)) { mL |= 1u << (J); lmL = i; cL++; } \
          rmx = fmaxf(rmx, (HC)); rmn = fminf(rmn, (HC)); hm = (HC); }
        #pragma unroll
        for (int q = 0; q < 4; q++) {
          float4 nxt = cur;
          float n0;
          if (q < 3) { nxt = *(const float4*)&hcur[physi(base + q * 4 + 4)]; n0 = nxt.x; }
          else       { n0 = (base + 16 < NL) ? hcur[physi(base + 16)] : 0.0f; }
          PKSTEP(q * 4 + 0, cur.x, cur.y)
          PKSTEP(q * 4 + 1, cur.y, cur.z)
          PKSTEP(q * 4 + 2, cur.z, cur.w)
          PKSTEP(q * 4 + 3, cur.w, n0)
          cur = nxt;
        }
        #undef PKSTEP
      }
      int fpU = mU ? (base + __ffs(mU) - 1) : NL;   // first own peak
      int fpL = mL ? (base + __ffs(mL) - 1) : NL;
      unsigned long long bUm = __ballot(mU != 0);
      unsigned long long bLm = __ballot(mL != 0);
      // wave summaries: owning lane stores directly (no scans)
      {
        int s;
        s = bUm ? (63 - __clzll((long long)bUm)) : 0;
        if (lane == s) wLU[wv] = bUm ? lmU : -1;
        s = bLm ? (63 - __clzll((long long)bLm)) : 0;
        if (lane == s) wLL[wv] = bLm ? lmL : -1;
        s = bUm ? (__ffsll(bUm) - 1) : 0;
        if (lane == s) wNU[wv] = bUm ? fpU : NL;
        s = bLm ? (__ffsll(bLm) - 1) : 0;
        if (lane == s) wNL[wv] = bLm ? fpL : NL;
      }
      // block peak-count totals (reduce only; same pairwise order as before)
      unsigned ict = ((unsigned)cU << 16) | (unsigned)cL;
      #pragma unroll
      for (int o = 1; o < 64; o <<= 1) {
        unsigned cc = __shfl_down(ict, o, 64);
        if (lane + o < 64) ict += cc;
      }
      if (lane == 0) wCT[wv] = ict;
      __syncthreads();   // S1
      if (t == 0) {      // serial combine + (instant) lagged conv resolve
        int aLU = -1, aLL = -1; unsigned tt = 0;
        for (int w = 0; w < NW; w++) {
          eLU[w] = aLU; aLU = max(aLU, wLU[w]);
          eLL[w] = aLL; aLL = max(aLL, wLL[w]);
          tt += wCT[w];
        }
        int aNU = NL, aNL = NL;
        for (int w = NW - 1; w >= 0; w--) {
          eNU[w] = aNU; aNU = min(aNU, wNU[w]);
          eNL[w] = aNL; aNL = min(aNL, wNL[w]);
        }
        sTot = tt;
        int flag = 0;
        if (it >= LAG) {
          int s = k * N_ITER + (it - LAG);
          while (__hip_atomic_load(&scnt[s * 16], __ATOMIC_ACQUIRE, __HIP_MEMORY_SCOPE_AGENT) < NB)
            __builtin_amdgcn_s_sleep(1);
          double m2 = __hip_atomic_load(&sdsl[s * 8 + 0], __ATOMIC_RELAXED, __HIP_MEMORY_SCOPE_AGENT);
          double h2 = __hip_atomic_load(&sdsl[s * 8 + 1], __ATOMIC_RELAXED, __HIP_MEMORY_SCOPE_AGENT);
          flag = (m2 / (h2 + 1e-8) < 0.05) ? 1 : 0;
        }
        sFlag = flag;
      }
      __syncthreads();   // S2
      if (sFlag) {       // conv at j = it-LAG: recover s_j, h frozen there
        int j = it - LAG;
        if (useRing) {
          const float* src = (j == 0) ? res : (myring + (size_t)(j % 3) * NL);
          #pragma unroll
          for (int q = 0; q < 4; q++) {
            int i0 = base + q * 4;
            float4 v = *(const float4*)&src[i0];
            *(float4*)&hcur[physi(i0)] = v;
          }
          __syncthreads();
        } else {
          off ^= HSZ;    // lag-1: s_{it-1} still in the other LDS buffer
        }
        fin = 1; break;
      }
      const unsigned tot = sTot;
      const int totU = (int)(tot >> 16), totL = (int)(tot & 0xffffu);

      // per-thread carries via ballot bit-ops + one dynamic shuffle each
      unsigned long long belowU = bUm & ((1ull << lane) - 1ull);
      unsigned long long belowL = bLm & ((1ull << lane) - 1ull);
      unsigned long long aboveU = (lane == 63) ? 0ull : (bUm & (~0ull << (lane + 1)));
      unsigned long long aboveL = (lane == 63) ? 0ull : (bLm & (~0ull << (lane + 1)));
      int slU = belowU ? (63 - __clzll((long long)belowU)) : 0;
      int slL = belowL ? (63 - __clzll((long long)belowL)) : 0;
      int snU = aboveU ? (__ffsll(aboveU) - 1) : 0;
      int snL = aboveL ? (__ffsll(aboveL) - 1) : 0;
      int gU  = __shfl(lmU, slU, 64);
      int gL  = __shfl(lmL, slL, 64);
      int gNU = __shfl(fpU, snU, 64);
      int gNL = __shfl(fpL, snL, 64);
      const int clU = belowU ? gU  : eLU[wv];
      const int clL = belowL ? gL  : eLL[wv];
      const int cnU = aboveU ? gNU : eNU[wv];
      const int cnL = aboveL ? gNL : eNL[wv];

      // Mx/Mn prefix carries only needed for the <2-peaks fallback (rare);
      // tot is block-uniform so the branch (and its barriers) is uniform.
      float crx = -FMAXV, crn = FMAXV;
      if (totU < 2 || totL < 2) {
        float iMx = rmx, iMn = rmn;
        #pragma unroll
        for (int o = 1; o < 64; o <<= 1) {
          float fa = __shfl_up(iMx, o, 64);
          float fb = __shfl_up(iMn, o, 64);
          if (lane >= o) { iMx = fmaxf(iMx, fa); iMn = fminf(iMn, fb); }
        }
        if (lane == 63) { wMx[wv] = iMx; wMn[wv] = iMn; }
        __syncthreads();
        if (t == 0) {
          float aMx = -FMAXV, aMn = FMAXV;
          for (int w = 0; w < NW; w++) {
            eMx[w] = aMx; aMx = fmaxf(aMx, wMx[w]);
            eMn[w] = aMn; aMn = fminf(aMn, wMn[w]);
          }
        }
        __syncthreads();
        float pMx = __shfl_up(iMx, 1, 64); if (lane == 0) pMx = -FMAXV;
        float pMn = __shfl_up(iMn, 1, 64); if (lane == 0) pMn = FMAXV;
        crx = fmaxf(eMx[wv], pMx);
        crn = fminf(eMn[wv], pMn);
      }

      // pass C: envelopes + mean (frozen f32 ladder), streaming b128 chunks;
      // h_next = hc - mn -> other LDS buffer AND ring[(it+1)%3] (snapshot).
      float* rdst = myring + (size_t)((it + 1) % 3) * NL;
      double pm2 = 0.0, ph2 = 0.0;
      {
        float rx = crx, rn = crn;
        int curLU = clU, curLL = clL;
        float vl = hcur[physi(clU < 0 ? 0 : clU)];   // carry-in gathers
        float wl = hcur[physi(clL < 0 ? 0 : clL)];
        int gB = -0x7fffffff, gD = -0x7fffffff;
        float vr = 0.0f, wr = 0.0f;
        #define ENVSTEP(J, HC, OD) { int i = base + (J); float hc = (HC);   \
          rx = fmaxf(rx, hc); rn = fminf(rn, hc);                           \
          if ((mU >> (J)) & 1u) { curLU = i; vl = hc; }                     \
          if ((mL >> (J)) & 1u) { curLL = i; wl = hc; }                     \
          int lU = curLU, lL = curLL;                                       \
          unsigned highm = 0xFFFFFFFFu << (J); unsigned a;                  \
          a = mU & highm; int nUv = a ? (base + __ffs(a) - 1) : cnU;        \
          a = mL & highm; int nLv = a ? (base + __ffs(a) - 1) : cnL;        \
          if (nUv != gB) { gB = nUv; vr = hcur[physi(nUv >= NL ? NL - 1 : nUv)]; } \
          if (nLv != gD) { gD = nLv; wr = hcur[physi(nLv >= NL ? NL - 1 : nLv)]; } \
          int den = nUv - lU;                                               \
          float fracU = (float)(i - lU) / (float)(den > 0 ? den : 1);       \
          float envU = (den > 0) ? __builtin_fmaf(fracU, vr - vl, vl) : vl; \
          if (lU < 0) envU = vr;                                            \
          if (nUv >= NL) envU = vl;                                         \
          if (totU < 2) envU = rx;                                          \
          int den2 = nLv - lL;                                              \
          float fracL = (float)(i - lL) / (float)(den2 > 0 ? den2 : 1);     \
          float envL = (den2 > 0) ? __builtin_fmaf(fracL, wr - wl, wl) : wl;\
          if (lL < 0) envL = wr;                                            \
          if (nLv >= NL) envL = wl;                                         \
          if (totL < 2) envL = rn;                                          \
          float mn = 0.5f * (envU + envL);                                  \
          (OD) = hc - mn;                                                   \
          pm2 += (double)mn * (double)mn; ph2 += (double)hc * (double)hc; }
        #pragma unroll
        for (int q = 0; q < 4; q++) {
          int i0 = base + q * 4;
          float4 hv4 = *(const float4*)&hcur[physi(i0)];
          float4 o4;
          ENVSTEP(q * 4 + 0, hv4.x, o4.x)
          ENVSTEP(q * 4 + 1, hv4.y, o4.y)
          ENVSTEP(q * 4 + 2, hv4.z, o4.z)
          ENVSTEP(q * 4 + 3, hv4.w, o4.w)
          *(float4*)&hnx[physi(i0)] = o4;
          if (useRing) *(float4*)&rdst[i0] = o4;   // block-private snapshot
        }
        #undef ENVSTEP
      }
      // fused block reduction of (pm2, ph2)
      #pragma unroll
      for (int o = 1; o < 64; o <<= 1) {
        double a = __shfl_down(pm2, o, 64);
        double b = __shfl_down(ph2, o, 64);
        if (lane + o < 64) { pm2 += a; ph2 += b; }
      }
      if (lane == 0) { tA[wv] = pm2; tB[wv] = ph2; }
      __syncthreads();   // S5: orders tA/tB + hnx writes (next pass A's dep)
      if (t == 0) {      // post partials + arrival -- NO WAIT
        double sA = 0.0, sB = 0.0;
        for (int w = 0; w < NW; w++) { sA += tA[w]; sB += tB[w]; }
        int s = k * N_ITER + it;
        atomicAdd(&sdsl[s * 8 + 0], sA);
        atomicAdd(&sdsl[s * 8 + 1], sB);
        __hip_atomic_fetch_add(&scnt[s * 16], 1u, __ATOMIC_ACQ_REL, __HIP_MEMORY_SCOPE_AGENT);
      }
      off ^= HSZ;        // accept h_next provisionally (revocable via ring)
    }
    if (!fin) {          // resolve trailing slots in order (first-true wins)
      for (int j = N_ITER - LAG; j < N_ITER; j++) {
        if (t == 0) {
          int s = k * N_ITER + j;
          while (__hip_atomic_load(&scnt[s * 16], __ATOMIC_ACQUIRE, __HIP_MEMORY_SCOPE_AGENT) < NB)
            __builtin_amdgcn_s_sleep(1);
          double m2 = __hip_atomic_load(&sdsl[s * 8 + 0], __ATOMIC_RELAXED, __HIP_MEMORY_SCOPE_AGENT);
          double h2 = __hip_atomic_load(&sdsl[s * 8 + 1], __ATOMIC_RELAXED, __HIP_MEMORY_SCOPE_AGENT);
          sFlag = (m2 / (h2 + 1e-8) < 0.05) ? 1 : 0;
        }
        __syncthreads();
        if (sFlag) {
          if (useRing) {   // j >= 10 here, so ring always holds s_j
            const float* src = myring + (size_t)(j % 3) * NL;
            float* hc = hbuf + off;
            #pragma unroll
            for (int q = 0; q < 4; q++) {
              int i0 = base + q * 4;
              float4 v = *(const float4*)&src[i0];
              *(float4*)&hc[physi(i0)] = v;
            }
            __syncthreads();
          } else {
            off ^= HSZ;    // lag-1 tail: j == 11, s_11 in other buffer
          }
          break;
        }
      }
    }

    float* hcur = hbuf + off;  // h_final

    // ---- resolve done_{k-1}: posted a full IMF ago -> instant ----
    if (k > 0) {
      if (t == 0) {
        while (__hip_atomic_load(&fcnt[(k - 1) * 16], __ATOMIC_ACQUIRE, __HIP_MEMORY_SCOPE_AGENT) < NB)
          __builtin_amdgcn_s_sleep(1);
        double S1 = __hip_atomic_load(&flsl[(k - 1) * 8 + 0], __ATOMIC_RELAXED, __HIP_MEMORY_SCOPE_AGENT);
        double S2 = __hip_atomic_load(&flsl[(k - 1) * 8 + 1], __ATOMIC_RELAXED, __HIP_MEMORY_SCOPE_AGENT);
        double S3 = __hip_atomic_load(&flsl[(k - 1) * 8 + 2], __ATOMIC_RELAXED, __HIP_MEMORY_SCOPE_AGENT);
        double S4 = __hip_atomic_load(&flsl[(k - 1) * 8 + 3], __ATOMIC_RELAXED, __HIP_MEMORY_SCOPE_AGENT);
        double nr = (double)NB * (double)NL;
        double nd = (double)NB * (double)(NL - 1);
        double varr = (S2 - S1 * S1 / nr) / (nr - 1.0);
        double vard = (S4 - S3 * S3 / nd) / (nd - 1.0);
        sFlag = (vard < 0.05 * varr) ? 1 : 0;
      }
      __syncthreads();
      if (sFlag) done = true;
    }
    if (done) {  // flat at k-1: this IMF's sifting is discarded (ref: zeros)
      #pragma unroll
      for (int q = 0; q < NC / 4; q++)
        *(float4*)&outk[base + q * 4] = make_float4(0.f, 0.f, 0.f, 0.f);
      continue;
    }

    // ------------- flatness partials (f32 values, f64 sums) -------------
    double s1 = 0.0, s2 = 0.0, s3 = 0.0, s4 = 0.0;
    {
      float rb = 0.0f;   // res-h at base+NC (next thread's first element)
      if (base + NC < NL) rb = res[base + NC] - hcur[physi(base + NC)];
      float4 rv4 = *(const float4*)&res[base];
      float4 hv4 = *(const float4*)&hcur[physi(base)];
      float e0 = rv4.x - hv4.x, e1 = rv4.y - hv4.y,
            e2 = rv4.z - hv4.z, e3 = rv4.w - hv4.w;
      #define FLSTEP(J, CUR, NXT) { int i = base + (J);                     \
        s1 += (double)(CUR); s2 += (double)(CUR) * (double)(CUR);           \
        if (i + 1 < NL) { float dd = (NXT) - (CUR);                         \
          s3 += (double)dd; s4 += (double)dd * (double)dd; } }
      #pragma unroll
      for (int q = 0; q < 4; q++) {
        float c0 = e0, c1 = e1, c2 = e2, c3 = e3;
        float n0;
        if (q < 3) {
          int i0 = base + q * 4 + 4;
          rv4 = *(const float4*)&res[i0];
          hv4 = *(const float4*)&hcur[physi(i0)];
          e0 = rv4.x - hv4.x; e1 = rv4.y - hv4.y;
          e2 = rv4.z - hv4.z; e3 = rv4.w - hv4.w;
          n0 = e0;
        } else n0 = rb;
        FLSTEP(q * 4 + 0, c0, c1)
        FLSTEP(q * 4 + 1, c1, c2)
        FLSTEP(q * 4 + 2, c2, c3)
        FLSTEP(q * 4 + 3, c3, n0)
      }
      #undef FLSTEP
    }
    #pragma unroll
    for (int o = 1; o < 64; o <<= 1) {
      double a = __shfl_down(s1, o, 64);
      double b = __shfl_down(s2, o, 64);
      double c = __shfl_down(s3, o, 64);
      double d = __shfl_down(s4, o, 64);
      if (lane + o < 64) { s1 += a; s2 += b; s3 += c; s4 += d; }
    }
    if (lane == 0) { tA[wv] = s1; tB[wv] = s2; tC[wv] = s3; tD[wv] = s4; }
    __syncthreads();   // orders publishes AND all cross-thread h/res reads above
    if (t == 0) {      // post flat partials + arrival -- NO WAIT (full-IMF lag)
      double S1 = 0.0, S2 = 0.0, S3 = 0.0, S4 = 0.0;
      for (int w = 0; w < NW; w++) { S1 += tA[w]; S2 += tB[w]; S3 += tC[w]; S4 += tD[w]; }
      atomicAdd(&flsl[k * 8 + 0], S1);
      atomicAdd(&flsl[k * 8 + 1], S2);
      atomicAdd(&flsl[k * 8 + 2], S3);
      atomicAdd(&flsl[k * 8 + 3], S4);
      __hip_atomic_fetch_add(&fcnt[k * 16], 1u, __ATOMIC_ACQ_REL, __HIP_MEMORY_SCOPE_AGENT);
    }
    // outputs: IMF k = h; res -= h; h <- new res (current buffer)
    #pragma unroll
    for (int q = 0; q < NC / 4; q++) {
      int i0 = base + q * 4;
      int p0 = physi(i0);
      float4 rv = *(const float4*)&res[i0];
      float4 hv = *(const float4*)&hcur[p0];
      float4 rq = make_float4(rv.x - hv.x, rv.y - hv.y, rv.z - hv.z, rv.w - hv.w);
      *(float4*)&outk[i0] = hv;
      *(float4*)&res[i0] = rq;
      *(float4*)&hcur[p0] = rq;
    }
    __syncthreads();   // orders h <- res writes before next IMF's pass A
  }
}

extern "C" void kernel_launch(void* const* d_in, const int* in_sizes, int n_in,
                              void* d_out, int out_size, void* d_ws, size_t ws_size,
                              hipStream_t stream) {
  const float* x = (const float*)d_in[0];
  float* out = (float*)d_out;
  // ws: [0] scnt 72x64B; [8192] sdsl 72x64B; [16384] fcnt 6x64B;
  //     [20480] flsl 6x64B; [32768] ring NB*3*NL floats (12.6MB)
  size_t needed = 32768 + (size_t)NB * 3 * NL * sizeof(float);
  int useRing = (ws_size >= needed) ? 1 : 0;
  size_t zb = ws_size < 32768 ? ws_size : 32768;
  hipMemsetAsync(d_ws, 0, zb, stream);
  hipLaunchKernelGGL(emd_main, dim3(NB), dim3(NT), 0, stream,
                     x, out, (char*)d_ws, useRing);
}